// Round 13
// baseline (13681.310 us; speedup 1.0000x reference)
//
#include <hip/hip_runtime.h>
#include <math.h>

#define B_N 32
#define T_N 1024
#define E_N 512
#define H_N 512

typedef __attribute__((ext_vector_type(8))) short short8;
typedef __attribute__((ext_vector_type(4))) float f32x4;
typedef __attribute__((ext_vector_type(4))) unsigned int uint32x4;
typedef unsigned long long ull;

__device__ __forceinline__ unsigned short f2bfu(float f) {
  unsigned int x = __builtin_bit_cast(unsigned int, f);
  x += 0x7fffu + ((x >> 16) & 1u);
  return (unsigned short)(x >> 16);
}
__device__ __forceinline__ float bfu2f(unsigned short u) {
  return __builtin_bit_cast(float, ((unsigned int)u) << 16);
}
__device__ __forceinline__ float sigmf(float x) { return 1.0f / (1.0f + expf(-x)); }

// ---- agent-scope (MALL-coherent, bypass L1/L2) helpers --------------------
__device__ __forceinline__ void load64_mall_nowait(const unsigned short* p,
                                                   uint32x4& a, uint32x4& b,
                                                   uint32x4& c, uint32x4& d) {
  asm volatile("global_load_dwordx4 %0, %4, off sc0 sc1\n\t"
               "global_load_dwordx4 %1, %4, off offset:16 sc0 sc1\n\t"
               "global_load_dwordx4 %2, %4, off offset:32 sc0 sc1\n\t"
               "global_load_dwordx4 %3, %4, off offset:48 sc0 sc1"
               : "=&v"(a), "=&v"(b), "=&v"(c), "=&v"(d)
               : "v"(p) : "memory");
}
// plain CACHED load (L1/L2/L3 path — xs is read-shared, we want caching)
__device__ __forceinline__ void loadf4_nowait(const float* p, f32x4& v) {
  asm volatile("global_load_dwordx4 %0, %1, off" : "=&v"(v) : "v"(p) : "memory");
}
__device__ __forceinline__ void store32_mall(unsigned int* p, unsigned int v) {
  asm volatile("global_store_dword %0, %1, off sc0 sc1" :: "v"(p), "v"(v) : "memory");
}
__device__ __forceinline__ void waitcnt_vm0() {
  asm volatile("s_waitcnt vmcnt(0)" ::: "memory");
}
// Pipelined 2-deep flag poll (R8). On exit up to ONE flag load outstanding —
// drained by the B-phase vmcnt(0) before any data use.
__device__ __forceinline__ void poll_flag2(const unsigned int* pf, unsigned int want) {
  unsigned int fa, fb;
  asm volatile("global_load_dword %0, %2, off sc0 sc1\n\t"
               "global_load_dword %1, %2, off sc0 sc1"
               : "=&v"(fa), "=&v"(fb) : "v"(pf) : "memory");
  for (;;) {
    asm volatile("s_waitcnt vmcnt(1)" ::: "memory");
    __builtin_amdgcn_sched_barrier(0);
    if (fa >= want) break;
    asm volatile("global_load_dword %0, %1, off sc0 sc1" : "=&v"(fa) : "v"(pf) : "memory");
    asm volatile("s_waitcnt vmcnt(1)" ::: "memory");
    __builtin_amdgcn_sched_barrier(0);
    if (fb >= want) break;
    asm volatile("global_load_dword %0, %1, off sc0 sc1" : "=&v"(fb) : "v"(pf) : "memory");
  }
}

// ---------------------------------------------------------------------------
// Persistent BiLSTM, 64 wgs x 512 threads, dir = wg&1, cg = wg>>1 (16 cols).
// R8 transport (per-wave flags + bulk MALL h exchange) — UNCHANGED.
// Fused x-projection with CORRECT load placement (R11/R12 lesson): the
// xs(t+1) loads are issued right after poll exit and drained by the SAME
// vmcnt(0) as the h MALL loads — cost = max(MALL_RT, xs_latency) ≈ MALL_RT.
// Nothing except publish stores is ever outstanding at F2's drain, and
// nothing except flag loads is outstanding at the poll's vmcnt(1).
// Xs2 stage writes use a cl-rotated store order (2-way banks instead of
// 8-way). Early stop at Lmax = lengths[0] (sorted descending).
// ---------------------------------------------------------------------------
__global__ __launch_bounds__(512, 1) void rec_kernel(
    const float* __restrict__ xs, const int* __restrict__ lengths,
    const float* __restrict__ w_ih_f, const float* __restrict__ b_f,
    const float* __restrict__ w_ih_b, const float* __restrict__ b_b,
    const float* __restrict__ w_hh_f, const float* __restrict__ w_hh_b,
    const float* __restrict__ w_cls,
    unsigned short* __restrict__ hx,         // [2][2][32][32][16] bf16
    unsigned int* __restrict__ flg,          // [2][32][8] u32
    float* __restrict__ lpart)               // [64 wg][B][T][2]
{
  __shared__ unsigned short Ah[32][520];       // 33.3 KB
  __shared__ unsigned short Xs2[2][32][520];   // 66.6 KB (double-buffered xs)
  __shared__ float gate_p[8][32][17];          // 17.4 KB

  const int tid = threadIdx.x;
  const int wg = blockIdx.x;
  const int dir = wg & 1;
  const int cg = wg >> 1;
  const int colbase = cg * 16;
  const float* __restrict__ w_hh = dir ? w_hh_b : w_hh_f;
  const float* __restrict__ w_ih = dir ? w_ih_b : w_ih_f;
  const float* __restrict__ bias = dir ? b_b : b_f;
  const int w = tid >> 6, lane = tid & 63;
  const int q = w >> 1, kh = w & 1;
  const int Lmax = lengths[0];                 // sorted descending -> max
  const int Tloc = (Lmax < T_N) ? Lmax : T_N;

  // one-time: W_hh and W_ih fragments (gate q, K-half kh) into registers
  short8 whh[8], wih[8];
  {
    const int grow = q * 512 + colbase + (lane & 15);
    const int kb = (lane >> 4) << 3;
    const float* __restrict__ rh = &w_hh[(size_t)grow * H_N + kh * 256];
    const float* __restrict__ ri = &w_ih[(size_t)grow * E_N + kh * 256];
#pragma unroll
    for (int ks = 0; ks < 8; ++ks) {
      float4 f0 = *(const float4*)&rh[ks * 32 + kb];
      float4 f1 = *(const float4*)&rh[ks * 32 + kb + 4];
      short8 v;
      v[0] = (short)f2bfu(f0.x); v[1] = (short)f2bfu(f0.y);
      v[2] = (short)f2bfu(f0.z); v[3] = (short)f2bfu(f0.w);
      v[4] = (short)f2bfu(f1.x); v[5] = (short)f2bfu(f1.y);
      v[6] = (short)f2bfu(f1.z); v[7] = (short)f2bfu(f1.w);
      whh[ks] = v;
      f0 = *(const float4*)&ri[ks * 32 + kb];
      f1 = *(const float4*)&ri[ks * 32 + kb + 4];
      v[0] = (short)f2bfu(f0.x); v[1] = (short)f2bfu(f0.y);
      v[2] = (short)f2bfu(f0.z); v[3] = (short)f2bfu(f0.w);
      v[4] = (short)f2bfu(f1.x); v[5] = (short)f2bfu(f1.y);
      v[6] = (short)f2bfu(f1.z); v[7] = (short)f2bfu(f1.w);
      wih[ks] = v;
    }
  }

  // per-thread epilogue ownership: b = tid>>4 (32), cl = tid&15 (16 cols)
  const int b = tid >> 4;
  const int cl = tid & 15;
  const int col = colbase + cl;
  const int Lb = lengths[b];
  float cc = 0.f, hh = 0.f;
  const float wc0 = w_cls[dir * H_N + col];
  const float wc1 = w_cls[2 * H_N + dir * H_N + col];
  const float bi  = bias[col];
  const float bff = bias[512 + col];
  const float bg  = bias[1024 + col];
  const float bo  = bias[1536 + col];

  float* __restrict__ lslice = lpart + (size_t)wg * B_N * T_N * 2;
  unsigned int* __restrict__ myflag = flg + ((size_t)dir * 32 + cg) * 8 + w;
  const unsigned int* __restrict__ pollflag =
      flg + ((size_t)dir * 32 + (tid >> 4)) * 8 + ((tid & 15) >> 1);

  const int b0 = (tid & 15) * 2, cg16 = (tid >> 4) * 16;

  // prologue: synchronously stage xs(0) into Xs2[0] (rotated store order)
  {
    const int st = dir ? (Lb - 1) : 0;
    const float* __restrict__ xrow = xs + ((size_t)b * T_N + st) * E_N + cl * 32;
    unsigned short* __restrict__ dst = &Xs2[0][b][cl * 32];
#pragma unroll
    for (int i = 0; i < 8; ++i) {
      const int ii = (i + cl) & 7;
      const float4 v = *(const float4*)&xrow[ii * 4];
      ushort4 u;
      u.x = f2bfu(v.x); u.y = f2bfu(v.y); u.z = f2bfu(v.z); u.w = f2bfu(v.w);
      *(ushort4*)&dst[ii * 4] = u;
    }
  }
  __syncthreads();

  for (int ts = 0; ts < Tloc; ++ts) {
    const int t = ts;
    const bool pfv = (t + 1 < Tloc);

    // B: poll producer-wave flag (only flag loads in flight here)
    poll_flag2(pollflag, (unsigned int)t);

    // B2: issue h MALL loads + xs(t+1) cached loads, ONE shared vmcnt(0).
    // xs latency (L3) overlaps the MALL round trip -> ~free (R10 pattern).
    f32x4 av[8];
    {
      uint32x4 va, vb, vc, vd;
      load64_mall_nowait(hx + ((size_t)dir * 2 + (t & 1)) * 16384 + (size_t)tid * 32,
                         va, vb, vc, vd);
      if (pfv) {
        const int tn = t + 1;
        const int st = (dir && tn < Lb) ? (Lb - 1 - tn) : tn;
        const float* __restrict__ xrow = xs + ((size_t)b * T_N + st) * E_N + cl * 32;
#pragma unroll
        for (int i = 0; i < 8; ++i) loadf4_nowait(&xrow[i * 4], av[i]);
      }
      waitcnt_vm0();  // drains h + xs + poll straggler together
      *(uint32x4*)&Ah[b0][cg16] = va;
      *(uint32x4*)&Ah[b0][cg16 + 8] = vb;
      *(uint32x4*)&Ah[b0 + 1][cg16] = vc;
      *(uint32x4*)&Ah[b0 + 1][cg16 + 8] = vd;
    }
    __syncthreads();  // S1: Ah complete

    // C: stage av (= xs(t+1)) into the other Xs buffer (rotated order)
    if (pfv) {
      unsigned short* __restrict__ dst = &Xs2[(t + 1) & 1][b][cl * 32];
#pragma unroll
      for (int i = 0; i < 8; ++i) {
        const int ii = (i + cl) & 7;
        ushort4 u;
        u.x = f2bfu(av[ii][0]); u.y = f2bfu(av[ii][1]);
        u.z = f2bfu(av[ii][2]); u.w = f2bfu(av[ii][3]);
        *(ushort4*)&dst[ii * 4] = u;
      }
    }

    // D: MFMA — wave w: gate q, K-half kh; h-term + x-term
    {
      f32x4 acc0 = {0.f, 0.f, 0.f, 0.f}, acc1 = {0.f, 0.f, 0.f, 0.f};
      const int kb = (lane >> 4) << 3;
      const unsigned short (*Xc)[520] = Xs2[t & 1];
#pragma unroll
      for (int ks = 0; ks < 8; ++ks) {
        const int kk = kh * 256 + (ks << 5) + kb;
        short8 a0 = *(const short8*)&Ah[(lane & 15)][kk];
        short8 a1 = *(const short8*)&Ah[16 + (lane & 15)][kk];
        acc0 = __builtin_amdgcn_mfma_f32_16x16x32_bf16(a0, whh[ks], acc0, 0, 0, 0);
        acc1 = __builtin_amdgcn_mfma_f32_16x16x32_bf16(a1, whh[ks], acc1, 0, 0, 0);
        short8 x0 = *(const short8*)&Xc[(lane & 15)][kk];
        short8 x1 = *(const short8*)&Xc[16 + (lane & 15)][kk];
        acc0 = __builtin_amdgcn_mfma_f32_16x16x32_bf16(x0, wih[ks], acc0, 0, 0, 0);
        acc1 = __builtin_amdgcn_mfma_f32_16x16x32_bf16(x1, wih[ks], acc1, 0, 0, 0);
      }
      const int crow = (lane >> 4) << 2;
      const int ccol = lane & 15;
#pragma unroll
      for (int j = 0; j < 4; ++j) {
        gate_p[w][crow + j][ccol] = acc0[j];
        gate_p[w][16 + crow + j][ccol] = acc1[j];
      }
    }
    __syncthreads();  // S2: gate_p ready

    // E: epilogue — merge K-halves, add bias, state update (fp32)
    const bool valid = (t < Lb);
    float hn;
    {
      const float gi = gate_p[0][b][cl] + gate_p[1][b][cl] + bi;
      const float gf = gate_p[2][b][cl] + gate_p[3][b][cl] + bff;
      const float gg = gate_p[4][b][cl] + gate_p[5][b][cl] + bg;
      const float go = gate_p[6][b][cl] + gate_p[7][b][cl] + bo;
      const float cn = sigmf(gf) * cc + sigmf(gi) * tanhf(gg);
      hn = sigmf(go) * tanhf(cn);
      if (valid) { cc = cn; hh = hn; }
    }

    // F1: publish h pair (MALL write-through); stores fly during G1
    {
      const float hhp = __shfl_xor(hh, 1);
      if ((cl & 1) == 0) {
        const unsigned int pv =
            (unsigned int)f2bfu(hh) | ((unsigned int)f2bfu(hhp) << 16);
        store32_mall((unsigned int*)(hx + ((size_t)dir * 2 + ((t + 1) & 1)) * 16384 +
                                     ((size_t)cg * 32 + b) * 16 + cl),
                     pv);
      }
    }
    // G1: logits shfl-reduce (VALU) — hides under publish store-ack
    float l0 = valid ? hn * wc0 : 0.f;
    float l1 = valid ? hn * wc1 : 0.f;
#pragma unroll
    for (int m = 8; m >= 1; m >>= 1) {
      l0 += __shfl_xor(l0, m);
      l1 += __shfl_xor(l1, m);
    }
    // F2: per-wave drain (only publish stores outstanding) + flag
    waitcnt_vm0();
    __builtin_amdgcn_sched_barrier(0);
    if (lane == 0)
      store32_mall(myflag, (unsigned int)(t + 1));
    // G2: lslice store (post-flag, off critical path); invalid -> zeros
    if (cl == 0) {
      float2 v;
      if (valid) {
        const int tpos = dir ? (Lb - 1 - t) : t;
        v.x = l0; v.y = l1;
        *(float2*)&lslice[((size_t)b * T_N + tpos) * 2] = v;
      } else {
        v.x = 0.f; v.y = 0.f;
        *(float2*)&lslice[((size_t)b * T_N + t) * 2] = v;
      }
    }
  }
}

// ---------------------------------------------------------------------------
__global__ void init_kernel(ull* __restrict__ hx64, unsigned int* __restrict__ flg)
{
  const int i = blockIdx.x * 256 + threadIdx.x;  // 0..16383
  if (i < 16384) hx64[i] = 0ull;                 // hx: 128 KB of zeros
  if (i < 1024) flg[i] = 0u;
}

__global__ void reduce_softmax_kernel(const float* __restrict__ lpart,
                                      const float* __restrict__ b_cls,
                                      const int* __restrict__ lengths,
                                      float* __restrict__ out)
{
  const int i = blockIdx.x * 256 + threadIdx.x;  // 0..32767
  if (i >= B_N * T_N) return;
  const int t = i & (T_N - 1);
  const int Lmax = lengths[0];
  float s0 = b_cls[0], s1 = b_cls[1];
  if (t < Lmax) {  // beyond Lmax lpart is unwritten (poison) — skip
    const float* __restrict__ p = lpart + (size_t)i * 2;
#pragma unroll 8
    for (int wg = 0; wg < 64; ++wg) {
      s0 += p[(size_t)wg * B_N * T_N * 2];
      s1 += p[(size_t)wg * B_N * T_N * 2 + 1];
    }
  }
  const float m = fmaxf(s0, s1);
  const float e0 = expf(s0 - m), e1 = expf(s1 - m);
  const float inv = 1.f / (e0 + e1);
  out[2 * i] = e0 * inv;
  out[2 * i + 1] = e1 * inv;
}

// ---------------------------------------------------------------------------
extern "C" void kernel_launch(void* const* d_in, const int* in_sizes, int n_in,
                              void* d_out, int out_size, void* d_ws, size_t ws_size,
                              hipStream_t stream)
{
  const float* xs      = (const float*)d_in[0];
  const int*   lengths = (const int*)d_in[1];
  // d_in[2] domains: unused (single-domain path)
  const float* w_ih_f  = (const float*)d_in[3];
  const float* w_hh_f  = (const float*)d_in[4];
  const float* b_f     = (const float*)d_in[5];
  const float* w_ih_b  = (const float*)d_in[6];
  const float* w_hh_b  = (const float*)d_in[7];
  const float* b_b     = (const float*)d_in[8];
  const float* w_cls   = (const float*)d_in[9];
  const float* b_cls   = (const float*)d_in[10];
  float* out = (float*)d_out;

  auto alignup = [](size_t v) { return (v + 255) & ~(size_t)255; };
  const size_t hx_b    = alignup((size_t)2 * 2 * 32 * 32 * 16 * 2);   // 128 KB
  const size_t flg_b   = alignup((size_t)1024 * 4);                   // 4 KB
  const size_t lpart_b = alignup((size_t)64 * B_N * T_N * 2 * 4);     // 16 MB

  char* p = (char*)d_ws;
  unsigned short* hx = (unsigned short*)p;  p += hx_b;
  unsigned int* flg = (unsigned int*)p;     p += flg_b;
  float* lpart = (float*)p;                 p += lpart_b;

  init_kernel<<<64, 256, 0, stream>>>((ull*)hx, flg);

  rec_kernel<<<64, 512, 0, stream>>>(xs, lengths, w_ih_f, b_f, w_ih_b, b_b,
                                     w_hh_f, w_hh_b, w_cls, hx, flg, lpart);

  reduce_softmax_kernel<<<128, 256, 0, stream>>>(lpart, b_cls, lengths, out);
}

// Round 14
// 3752.440 us; speedup vs baseline: 3.6460x; 3.6460x over previous
//
#include <hip/hip_runtime.h>
#include <math.h>

#define B_N 32
#define T_N 1024
#define E_N 512
#define H_N 512
#define G4_N 2048  // 4*H

typedef __attribute__((ext_vector_type(8))) short short8;
typedef __attribute__((ext_vector_type(4))) float f32x4;
typedef __attribute__((ext_vector_type(4))) unsigned int uint32x4;
typedef unsigned long long ull;

__device__ __forceinline__ unsigned short f2bfu(float f) {
  unsigned int x = __builtin_bit_cast(unsigned int, f);
  x += 0x7fffu + ((x >> 16) & 1u);
  return (unsigned short)(x >> 16);
}
__device__ __forceinline__ float bfu2f(unsigned short u) {
  return __builtin_bit_cast(float, ((unsigned int)u) << 16);
}
__device__ __forceinline__ float sigmf(float x) { return 1.0f / (1.0f + expf(-x)); }

// ---- agent-scope (MALL-coherent, bypass L1/L2) helpers (R6, verified) -----
__device__ __forceinline__ void load64_mall(const unsigned short* p,
                                            uint32x4& a, uint32x4& b,
                                            uint32x4& c, uint32x4& d) {
  asm volatile("global_load_dwordx4 %0, %4, off sc0 sc1\n\t"
               "global_load_dwordx4 %1, %4, off offset:16 sc0 sc1\n\t"
               "global_load_dwordx4 %2, %4, off offset:32 sc0 sc1\n\t"
               "global_load_dwordx4 %3, %4, off offset:48 sc0 sc1\n\t"
               "s_waitcnt vmcnt(0)"
               : "=&v"(a), "=&v"(b), "=&v"(c), "=&v"(d)
               : "v"(p) : "memory");
}
__device__ __forceinline__ void store32_mall(unsigned int* p, unsigned int v) {
  asm volatile("global_store_dword %0, %1, off sc0 sc1" :: "v"(p), "v"(v) : "memory");
}

// ---------------------------------------------------------------------------
// Kernel 1 (R6 verbatim): xw[dir][tl][g][b] bf16 = W_ih[dir] @ x(+rev) + b
// Used only for segment 0; later segments are produced by fused_kernel's
// GEMM role one segment ahead.
// ---------------------------------------------------------------------------
__global__ __launch_bounds__(256) void xw_gemm_kernel(
    const float* __restrict__ xs, const int* __restrict__ lengths,
    const float* __restrict__ w_ih_f, const float* __restrict__ b_f,
    const float* __restrict__ w_ih_b, const float* __restrict__ b_b,
    unsigned short* __restrict__ xw, int t0, int Tseg)
{
  __shared__ unsigned short As[64][80];
  __shared__ unsigned short Bs[64][80];
  const int g0 = blockIdx.x * 64;
  const int n0 = blockIdx.y * 64;
  const int dir = blockIdx.z;
  const float* __restrict__ W = dir ? w_ih_b : w_ih_f;
  const float* __restrict__ bias = dir ? b_b : b_f;
  const int tid = threadIdx.x;
  const int w = tid >> 6, lane = tid & 63;
  const int wr = w >> 1, wc = w & 1;

  const int sr = tid >> 2;
  const int sq = tid & 3;
  const int nrow = n0 + sr;
  const int bb = nrow & 31;
  const int tt = t0 + (nrow >> 5);
  const int Lb = lengths[bb];
  const int src_t = (dir != 0 && tt < Lb) ? (Lb - 1 - tt) : tt;
  const float* __restrict__ xrow = xs + ((size_t)bb * T_N + src_t) * E_N;
  const float* __restrict__ arow = W + (size_t)(g0 + sr) * E_N;

  f32x4 acc[2][2] = {};

  for (int k0 = 0; k0 < E_N; k0 += 64) {
    float4 av[4], bv[4];
#pragma unroll
    for (int i = 0; i < 4; ++i) {
      av[i] = *(const float4*)&arow[k0 + sq * 16 + i * 4];
      bv[i] = *(const float4*)&xrow[k0 + sq * 16 + i * 4];
    }
    __syncthreads();
#pragma unroll
    for (int i = 0; i < 4; ++i) {
      ushort4 a4, b4;
      a4.x = f2bfu(av[i].x); a4.y = f2bfu(av[i].y); a4.z = f2bfu(av[i].z); a4.w = f2bfu(av[i].w);
      b4.x = f2bfu(bv[i].x); b4.y = f2bfu(bv[i].y); b4.z = f2bfu(bv[i].z); b4.w = f2bfu(bv[i].w);
      *(ushort4*)&As[sr][sq * 16 + i * 4] = a4;
      *(ushort4*)&Bs[sr][sq * 16 + i * 4] = b4;
    }
    __syncthreads();
#pragma unroll
    for (int kk = 0; kk < 2; ++kk) {
      const int ko = kk * 32 + ((lane >> 4) << 3);
      short8 bf0 = *(const short8*)&Bs[wc * 32 + (lane & 15)][ko];
      short8 bf1 = *(const short8*)&Bs[wc * 32 + 16 + (lane & 15)][ko];
      short8 af0 = *(const short8*)&As[wr * 32 + (lane & 15)][ko];
      short8 af1 = *(const short8*)&As[wr * 32 + 16 + (lane & 15)][ko];
      acc[0][0] = __builtin_amdgcn_mfma_f32_16x16x32_bf16(af0, bf0, acc[0][0], 0, 0, 0);
      acc[0][1] = __builtin_amdgcn_mfma_f32_16x16x32_bf16(af0, bf1, acc[0][1], 0, 0, 0);
      acc[1][0] = __builtin_amdgcn_mfma_f32_16x16x32_bf16(af1, bf0, acc[1][0], 0, 0, 0);
      acc[1][1] = __builtin_amdgcn_mfma_f32_16x16x32_bf16(af1, bf1, acc[1][1], 0, 0, 0);
    }
  }

#pragma unroll
  for (int mt = 0; mt < 2; ++mt)
#pragma unroll
    for (int nt = 0; nt < 2; ++nt)
#pragma unroll
      for (int j = 0; j < 4; ++j) {
        const int m = g0 + wr * 32 + mt * 16 + ((lane >> 4) << 2) + j;
        const int n = n0 + wc * 32 + nt * 16 + (lane & 15);
        const int tl = n >> 5, b = n & 31;
        const float v = acc[mt][nt][j] + bias[m];
        xw[(((size_t)dir * Tseg + tl) * G4_N + m) * B_N + b] = f2bfu(v);
      }
}

// ---------------------------------------------------------------------------
// Fused kernel: blocks 0..63 = R6 rec (segment s, xw_cur); blocks 64..255 =
// GEMM producing xw_nxt for segment s+1 with PLAIN cached stores (consumed
// only by the NEXT dispatch -> kernel-boundary coherence; zero intra-dispatch
// dependencies; no sc0/sc1 write-through flood). LDS padded to 84KB forces
// 1 block/CU: the 64 rec blocks own their CUs exclusively.
// Early stop: Tloc = min(Tseg, Lmax - t0), Lmax = lengths[0] (sorted desc) —
// uniform across wgs, so the lockstep flag protocol is preserved.
// ---------------------------------------------------------------------------
__global__ __launch_bounds__(512, 1) void fused_kernel(
    const float* __restrict__ xs, const int* __restrict__ lengths,
    const float* __restrict__ w_ih_f, const float* __restrict__ b_f,
    const float* __restrict__ w_ih_b, const float* __restrict__ b_b,
    const float* __restrict__ w_hh_f, const float* __restrict__ w_hh_b,
    const float* __restrict__ w_cls,
    const unsigned short* __restrict__ xw_cur,  // [2][Tseg][2048][32] bf16
    unsigned short* __restrict__ xw_nxt,        // next segment's buffer
    unsigned short* __restrict__ hx,            // [2][2][32][32][16] bf16
    unsigned int* __restrict__ flg,             // [2][32][16] u32
    float* __restrict__ c_buf,                  // [2][B][H]
    float* __restrict__ lpart,                  // [64 wg][B][T][2]
    int t0, int Tseg, int t0n)
{
  __shared__ alignas(16) unsigned char smem[86016];  // 84KB -> 1 block/CU
  const int tid = threadIdx.x;
  const int w = tid >> 6, lane = tid & 63;
  const int Lmax = lengths[0];

  if (blockIdx.x >= 64) {
    // ===================== GEMM role: xw for segment s+1 =====================
    if (t0n >= T_N || t0n >= Lmax) return;
    unsigned short* As = (unsigned short*)smem;            // [64][80]
    unsigned short* Bs = (unsigned short*)(smem + 10240);  // [64][80]
    const int g = blockIdx.x - 64;              // 0..191
    const int wr = w >> 2, wc = w & 3;          // 8 waves: 2(m) x 4(n)
    const int sr = tid >> 3, sq = tid & 7;      // staging: 8 thr/row x 8 floats
    const int ntau = 2 * 32 * (Tseg >> 1);      // dirs x gtiles x ntiles

    for (int tau = g; tau < ntau; tau += 192) {
      const int gtile = tau & 31;
      const int rest = tau >> 5;
      const int dir = rest & 1;
      const int ntile = rest >> 1;
      const int tt0 = t0n + ntile * 2;
      if (tt0 >= Lmax) continue;                // block-uniform: barrier-safe
      const int g0 = gtile * 64;
      const float* __restrict__ W = dir ? w_ih_b : w_ih_f;
      const float* __restrict__ bias = dir ? b_b : b_f;
      const int bb = sr & 31;
      const int tt = tt0 + (sr >> 5);
      const int Lb2 = lengths[bb];
      const int src_t = (dir != 0 && tt < Lb2) ? (Lb2 - 1 - tt) : tt;
      const float* __restrict__ xrow = xs + ((size_t)bb * T_N + src_t) * E_N;
      const float* __restrict__ arow = W + (size_t)(g0 + sr) * E_N;
      f32x4 accm0 = {0.f, 0.f, 0.f, 0.f}, accm1 = {0.f, 0.f, 0.f, 0.f};

      for (int k0 = 0; k0 < E_N; k0 += 64) {
        const float4 av0 = *(const float4*)&arow[k0 + sq * 8];
        const float4 av1 = *(const float4*)&arow[k0 + sq * 8 + 4];
        const float4 bv0 = *(const float4*)&xrow[k0 + sq * 8];
        const float4 bv1 = *(const float4*)&xrow[k0 + sq * 8 + 4];
        __syncthreads();  // protect previous iteration's fragment reads
        ushort4 u;
        u.x = f2bfu(av0.x); u.y = f2bfu(av0.y); u.z = f2bfu(av0.z); u.w = f2bfu(av0.w);
        *(ushort4*)&As[sr * 80 + sq * 8] = u;
        u.x = f2bfu(av1.x); u.y = f2bfu(av1.y); u.z = f2bfu(av1.z); u.w = f2bfu(av1.w);
        *(ushort4*)&As[sr * 80 + sq * 8 + 4] = u;
        u.x = f2bfu(bv0.x); u.y = f2bfu(bv0.y); u.z = f2bfu(bv0.z); u.w = f2bfu(bv0.w);
        *(ushort4*)&Bs[sr * 80 + sq * 8] = u;
        u.x = f2bfu(bv1.x); u.y = f2bfu(bv1.y); u.z = f2bfu(bv1.z); u.w = f2bfu(bv1.w);
        *(ushort4*)&Bs[sr * 80 + sq * 8 + 4] = u;
        __syncthreads();
#pragma unroll
        for (int kk = 0; kk < 2; ++kk) {
          const int ko = kk * 32 + ((lane >> 4) << 3);
          short8 bf  = *(const short8*)&Bs[(wc * 16 + (lane & 15)) * 80 + ko];
          short8 af0 = *(const short8*)&As[(wr * 32 + (lane & 15)) * 80 + ko];
          short8 af1 = *(const short8*)&As[(wr * 32 + 16 + (lane & 15)) * 80 + ko];
          accm0 = __builtin_amdgcn_mfma_f32_16x16x32_bf16(af0, bf, accm0, 0, 0, 0);
          accm1 = __builtin_amdgcn_mfma_f32_16x16x32_bf16(af1, bf, accm1, 0, 0, 0);
        }
      }
      // epilogue: PLAIN cached stores (next-dispatch consumption)
#pragma unroll
      for (int mt = 0; mt < 2; ++mt)
#pragma unroll
        for (int j = 0; j < 4; ++j) {
          const int m = g0 + wr * 32 + mt * 16 + ((lane >> 4) << 2) + j;
          const int n = ntile * 64 + wc * 16 + (lane & 15);
          const int tl = n >> 5, b = n & 31;
          const float v = (mt ? accm1[j] : accm0[j]) + bias[m];
          xw_nxt[(((size_t)dir * Tseg + tl) * G4_N + m) * B_N + b] = f2bfu(v);
        }
    }
    return;
  }

  // ===================== REC role: R6 verbatim + Tloc clamp =====================
  unsigned short (*Ah)[520] = (unsigned short (*)[520])smem;          // 33280B
  float (*gate_p)[32][17] = (float (*)[32][17])(smem + 33280);        // 17408B
  float (*lp)[33][2] = (float (*)[33][2])(smem + 50688);              // 4224B

  const int wg = blockIdx.x;
  const int dir = wg & 1;
  const int cg = wg >> 1;
  const int colbase = cg * 16;
  const float* __restrict__ w_hh = dir ? w_hh_b : w_hh_f;
  const int q = w >> 1, kh = w & 1;
  const int Tloc = min(Tseg, max(0, Lmax - t0));

  // one-time: W_hh fragments (gate q, K-half kh) into registers
  short8 wfrag[8];
  {
    const int grow = q * 512 + colbase + (lane & 15);
    const int kb = (lane >> 4) << 3;
    const float* __restrict__ wr_ = &w_hh[(size_t)grow * H_N + kh * 256];
#pragma unroll
    for (int ks = 0; ks < 8; ++ks) {
      const float4 f0 = *(const float4*)&wr_[ks * 32 + kb];
      const float4 f1 = *(const float4*)&wr_[ks * 32 + kb + 4];
      short8 v;
      v[0] = (short)f2bfu(f0.x); v[1] = (short)f2bfu(f0.y);
      v[2] = (short)f2bfu(f0.z); v[3] = (short)f2bfu(f0.w);
      v[4] = (short)f2bfu(f1.x); v[5] = (short)f2bfu(f1.y);
      v[6] = (short)f2bfu(f1.z); v[7] = (short)f2bfu(f1.w);
      wfrag[ks] = v;
    }
  }

  // per-thread epilogue ownership: b = tid>>4 (32), cl = tid&15 (16 cols)
  const int b = tid >> 4;
  const int cl = tid & 15;
  const int col = colbase + cl;
  const int Lb = lengths[b];
  const int Lb_r = lengths[tid & 31];      // for the tid<64 logits reducer
  float cc = c_buf[((size_t)dir * B_N + b) * H_N + col];
  const float wc0 = w_cls[dir * H_N + col];
  const float wc1 = w_cls[2 * H_N + dir * H_N + col];

  // initial h (own column) — plain load: caches fresh at dispatch boundary
  float hh = bfu2f(hx[((size_t)dir * 2 + (t0 & 1)) * 16384 + ((size_t)cg * 32 + b) * 16 + cl]);

  float* __restrict__ lslice = lpart + (size_t)wg * B_N * T_N * 2;
  unsigned int* __restrict__ myflag = flg + dir * 512 + cg * 16;
  unsigned int* __restrict__ pollflag = flg + dir * 512 + (tid >> 4) * 16;

  // prefetch step-0 xw gate values (plain cached loads)
  unsigned short xv[4];
  if (Tloc > 0) {
    const unsigned short* __restrict__ xb =
        &xw_cur[((size_t)(dir * Tseg) * G4_N + colbase + cl) * B_N + b];
#pragma unroll
    for (int q2 = 0; q2 < 4; ++q2) xv[q2] = xb[(size_t)q2 * 512 * B_N];
  }

  const int b0 = (tid & 15) * 2, cg16 = (tid >> 4) * 16;

  for (int ts = 0; ts < Tloc; ++ts) {
    const int t = t0 + ts;

    // previous step's logits reduce FIRST — hides under the flag wait
    if (ts > 0 && tid < 64) {
      const int br = tid & 31, tau = tid >> 5;
      const int tp = t - 1;
      if (tp < Lb_r) {
        float s = 0.f;
#pragma unroll
        for (int k = 0; k < 16; ++k) s += lp[k][br][tau];
        const int tpos = dir ? (Lb_r - 1 - tp) : tp;
        lslice[((size_t)br * T_N + tpos) * 2 + tau] = s;
      }
    }

    // wait for the one producer whose slice this thread stages (cg' = tid>>4)
    {
      const unsigned int want = (unsigned int)t;
      while (__hip_atomic_load(pollflag, __ATOMIC_RELAXED, __HIP_MEMORY_SCOPE_AGENT) < want) {}
    }
    // bulk-load own 64B h slice (MALL) and place into Ah
    {
      uint32x4 va, vb, vc, vd;
      load64_mall(hx + ((size_t)dir * 2 + (t & 1)) * 16384 + (size_t)tid * 32,
                  va, vb, vc, vd);
      *(uint32x4*)&Ah[b0][cg16] = va;
      *(uint32x4*)&Ah[b0][cg16 + 8] = vb;
      *(uint32x4*)&Ah[b0 + 1][cg16] = vc;
      *(uint32x4*)&Ah[b0 + 1][cg16 + 8] = vd;
    }
    __syncthreads();  // SYNC1: Ah complete

    // MFMA: wave w computes gate q, K-half kh partials
    {
      f32x4 acc0 = {0.f, 0.f, 0.f, 0.f}, acc1 = {0.f, 0.f, 0.f, 0.f};
      const int kb = (lane >> 4) << 3;
#pragma unroll
      for (int ks = 0; ks < 8; ++ks) {
        const int kk = kh * 256 + (ks << 5) + kb;
        short8 a0 = *(const short8*)&Ah[(lane & 15)][kk];
        short8 a1 = *(const short8*)&Ah[16 + (lane & 15)][kk];
        acc0 = __builtin_amdgcn_mfma_f32_16x16x32_bf16(a0, wfrag[ks], acc0, 0, 0, 0);
        acc1 = __builtin_amdgcn_mfma_f32_16x16x32_bf16(a1, wfrag[ks], acc1, 0, 0, 0);
      }
      const int crow = (lane >> 4) << 2;
      const int ccol = lane & 15;
#pragma unroll
      for (int j = 0; j < 4; ++j) {
        gate_p[w][crow + j][ccol] = acc0[j];
        gate_p[w][16 + crow + j][ccol] = acc1[j];
      }
    }
    __syncthreads();  // SYNC2: gate_p ready

    // epilogue: merge K-halves, gates + state update (fp32)
    const bool valid = (t < Lb);
    float hn;
    {
      const float gi = gate_p[0][b][cl] + gate_p[1][b][cl] + bfu2f(xv[0]);
      const float gf = gate_p[2][b][cl] + gate_p[3][b][cl] + bfu2f(xv[1]);
      const float gg = gate_p[4][b][cl] + gate_p[5][b][cl] + bfu2f(xv[2]);
      const float go = gate_p[6][b][cl] + gate_p[7][b][cl] + bfu2f(xv[3]);
      const float cn = sigmf(gf) * cc + sigmf(gi) * tanhf(gg);
      hn = sigmf(go) * tanhf(cn);
      if (valid) { cc = cn; hh = hn; }
    }

    // publish h pair (MALL write-through); adjacent cols packed via shfl
    {
      const float hhp = __shfl_xor(hh, 1);
      if ((cl & 1) == 0) {
        const unsigned int pv =
            (unsigned int)f2bfu(hh) | ((unsigned int)f2bfu(hhp) << 16);
        store32_mall((unsigned int*)(hx + ((size_t)dir * 2 + ((t + 1) & 1)) * 16384 +
                                     ((size_t)cg * 32 + b) * 16 + cl),
                     pv);
      }
    }
    lp[cl][b][0] = valid ? hn * wc0 : 0.f;
    lp[cl][b][1] = valid ? hn * wc1 : 0.f;

    __syncthreads();  // SYNC3: barrier drains vmcnt(0) -> all slices at MALL
    if (tid == 0)
      __hip_atomic_store(myflag, (unsigned int)(t + 1),
                         __ATOMIC_RELAXED, __HIP_MEMORY_SCOPE_AGENT);

    // prefetch next step's xw (completes under next poll/MFMA)
    if (ts + 1 < Tloc) {
      const unsigned short* __restrict__ xb =
          &xw_cur[((size_t)(dir * Tseg + ts + 1) * G4_N + colbase + cl) * B_N + b];
#pragma unroll
      for (int q2 = 0; q2 < 4; ++q2) xv[q2] = xb[(size_t)q2 * 512 * B_N];
    }
  }

  // final step's logits reduce
  if (Tloc > 0 && tid < 64) {
    const int br = tid & 31, tau = tid >> 5;
    const int tp = t0 + Tloc - 1;
    if (tp < Lb_r) {
      float s = 0.f;
#pragma unroll
      for (int k = 0; k < 16; ++k) s += lp[k][br][tau];
      const int tpos = dir ? (Lb_r - 1 - tp) : tp;
      lslice[((size_t)br * T_N + tpos) * 2 + tau] = s;
    }
  }

  // persist c across segment launches (h persists via hx)
  c_buf[((size_t)dir * B_N + b) * H_N + col] = cc;
}

// ---------------------------------------------------------------------------
__global__ void init_kernel(ull* __restrict__ hx64, float* __restrict__ c_buf,
                            unsigned int* __restrict__ flg)
{
  const int i = blockIdx.x * 256 + threadIdx.x;  // 0..65535
  if (i < 16384) hx64[i] = 0ull;                 // hx: 128 KB of zeros
  if (i < 2 * B_N * H_N) c_buf[i] = 0.f;
  if (i < 1024) flg[i] = 0u;
}

__global__ void reduce_softmax_kernel(const float* __restrict__ lpart,
                                      const float* __restrict__ b_cls,
                                      float* __restrict__ out)
{
  const int i = blockIdx.x * 256 + threadIdx.x;  // 0..32767
  if (i >= B_N * T_N) return;
  float s0 = b_cls[0], s1 = b_cls[1];
  const float* __restrict__ p = lpart + (size_t)i * 2;
#pragma unroll 8
  for (int wg = 0; wg < 64; ++wg) {
    s0 += p[(size_t)wg * B_N * T_N * 2];
    s1 += p[(size_t)wg * B_N * T_N * 2 + 1];
  }
  const float m = fmaxf(s0, s1);
  const float e0 = expf(s0 - m), e1 = expf(s1 - m);
  const float inv = 1.f / (e0 + e1);
  out[2 * i] = e0 * inv;
  out[2 * i + 1] = e1 * inv;
}

// ---------------------------------------------------------------------------
extern "C" void kernel_launch(void* const* d_in, const int* in_sizes, int n_in,
                              void* d_out, int out_size, void* d_ws, size_t ws_size,
                              hipStream_t stream)
{
  const float* xs      = (const float*)d_in[0];
  const int*   lengths = (const int*)d_in[1];
  // d_in[2] domains: unused (single-domain path)
  const float* w_ih_f  = (const float*)d_in[3];
  const float* w_hh_f  = (const float*)d_in[4];
  const float* b_f     = (const float*)d_in[5];
  const float* w_ih_b  = (const float*)d_in[6];
  const float* w_hh_b  = (const float*)d_in[7];
  const float* b_b     = (const float*)d_in[8];
  const float* w_cls   = (const float*)d_in[9];
  const float* b_cls   = (const float*)d_in[10];
  float* out = (float*)d_out;

  auto alignup = [](size_t v) { return (v + 255) & ~(size_t)255; };
  const size_t hx_b    = alignup((size_t)2 * 2 * 32 * 32 * 16 * 2);   // 128 KB
  const size_t flg_b   = alignup((size_t)1024 * 4);                   // 4 KB
  const size_t cbuf_b  = alignup((size_t)2 * B_N * H_N * 4);          // 128 KB
  const size_t lpart_b = alignup((size_t)64 * B_N * T_N * 2 * 4);     // 16 MB
  const size_t fixed = hx_b + flg_b + cbuf_b + lpart_b + 1024;

  // nseg with TWO xw segment buffers (current + next)
  int nseg = 1;
  while (nseg < 64) {
    const size_t xwb = alignup((size_t)2 * (T_N / nseg) * G4_N * B_N * 2);
    if (2 * xwb + fixed <= ws_size) break;
    nseg <<= 1;
  }
  const int Tseg = T_N / nseg;
  const size_t xw_b = alignup((size_t)2 * Tseg * G4_N * B_N * 2);

  char* p = (char*)d_ws;
  unsigned short* xw0 = (unsigned short*)p; p += xw_b;
  unsigned short* xw1 = (unsigned short*)p; p += xw_b;
  unsigned short* hx = (unsigned short*)p;  p += hx_b;
  unsigned int* flg = (unsigned int*)p;     p += flg_b;
  float* c_buf = (float*)p;                 p += cbuf_b;
  float* lpart = (float*)p;                 p += lpart_b;
  unsigned short* bufs[2] = {xw0, xw1};

  hipMemsetAsync(lpart, 0, lpart_b, stream);
  init_kernel<<<256, 256, 0, stream>>>((ull*)hx, c_buf, flg);

  // segment 0's xw: standalone GEMM (R6 kernel)
  {
    dim3 g(G4_N / 64, (Tseg * B_N) / 64, 2);
    xw_gemm_kernel<<<g, 256, 0, stream>>>(xs, lengths, w_ih_f, b_f, w_ih_b, b_b,
                                          bufs[0], 0, Tseg);
  }

  for (int s = 0; s < nseg; ++s) {
    const int t0 = s * Tseg;
    fused_kernel<<<256, 512, 0, stream>>>(
        xs, lengths, w_ih_f, b_f, w_ih_b, b_b, w_hh_f, w_hh_b, w_cls,
        bufs[s & 1], bufs[(s + 1) & 1], hx, flg, c_buf, lpart,
        t0, Tseg, t0 + Tseg);
  }

  reduce_softmax_kernel<<<128, 256, 0, stream>>>(lpart, b_cls, out);
}